// Round 8
// baseline (369.641 us; speedup 1.0000x reference)
//
#include <hip/hip_runtime.h>
#include <math.h>

// GCN 3-layer + classifier — round 18: DISCRIMINATING experiment on build_lin.
// Round-17 (HB=1024 + reg-staged sortbin) passed at 353us; build_lin still 88us
// (VALU 12%, HBM 18%, occ 72% -> stall-bound). Two theories, opposite predictions
// for HB=512 (EPB 4096, 32.6KB LDS -> 4 blocks/CU):
//   (1) barrier-domain: 2->4 domains/CU hides phase stalls -> build ~65us
//   (2) cursor-chain: 782->1563 blocks doubles per-bin global-atomic RMW chains
//       on cursor[] -> build ~100us
// Either outcome picks next round's lever. vs round 15: lin role's divergent
// break+shfl replaced with clamp+predicated store (UB hygiene).
//
// Math identity: agg[d] = dinv[d]*( g[d] + sum_{in} g[s] ),  g = dinv*h.

#define NR 500
#define RNG 400
#define CAP 16384            // slots per bin (expect ~12800 +- 113); = 16*1024
#define HB 512               // build threads (experiment: was 1024)
#define EPT 8                // build edges per thread
#define EPB (HB * EPT)       // 4096 edges per build block
#define SCAP 14348           // sortbin LDS buffer (mean+13 sigma, 4-aligned)
#define QBLK 100             // dst nodes per bagg block (RNG/4)
#define LINR 64              // rows per lin-role block

// ---------------- init: cursors + zero sentinel g-rows ----------------

__global__ void k_initcur(int* __restrict__ cursor, float* __restrict__ g1,
                          float* __restrict__ g2, float* __restrict__ g3, int n) {
    int t = blockIdx.x * blockDim.x + threadIdx.x;
    if (t < NR) cursor[t * 16] = t * CAP;
    if (t < 4) g1[4 * (size_t)n + t] = 0.0f;
    if (t >= 4 && t < 8) g2[4 * (size_t)n + (t - 4)] = 0.0f;
    if (t >= 8 && t < 10) g3[2 * (size_t)n + (t - 8)] = 0.0f;
}

// ---------------- build (bin by dst/400) + fused h1 = x @ W1 ----------------

__global__ __launch_bounds__(HB) void k_build_lin(const int* __restrict__ src,
                                                  const int* __restrict__ dst,
                                                  int* __restrict__ cursor,
                                                  int* __restrict__ csrp,
                                                  const float* __restrict__ x,
                                                  const float* __restrict__ W1,
                                                  float4* __restrict__ h1,
                                                  int e, int n, int nBuild) {
    __shared__ int hist[NR];
    __shared__ int start[NR + 1];
    __shared__ int gbase[NR];
    __shared__ int cur[NR];
    __shared__ int wsum[8];
    __shared__ int buf[EPB];
    __shared__ short bbin[EPB];

    int t = threadIdx.x;
    int b = blockIdx.x;

    if (b >= nBuild) {
        // ---- lin role: h1[row] = x[row,:] @ W1, 32 threads per row ----
        int row0 = (b - nBuild) * LINR;
        int q = t & 31, r = t >> 5;          // k-slice q (4 floats), row-group r (0..15)
#pragma unroll
        for (int rr = 0; rr < 4; rr++) {
            int row = row0 + rr * 16 + r;
            int rowc = (row < n) ? row : (n - 1);   // clamp (no divergent break)
            float4 xv = ((const float4*)(x + (size_t)rowc * 128))[q];
            float4 w0 = ((const float4*)W1)[q * 4 + 0];
            float4 w1 = ((const float4*)W1)[q * 4 + 1];
            float4 w2 = ((const float4*)W1)[q * 4 + 2];
            float4 w3 = ((const float4*)W1)[q * 4 + 3];
            float p0 = xv.x * w0.x + xv.y * w1.x + xv.z * w2.x + xv.w * w3.x;
            float p1 = xv.x * w0.y + xv.y * w1.y + xv.z * w2.y + xv.w * w3.y;
            float p2 = xv.x * w0.z + xv.y * w1.z + xv.z * w2.z + xv.w * w3.z;
            float p3 = xv.x * w0.w + xv.y * w1.w + xv.z * w2.w + xv.w * w3.w;
#pragma unroll
            for (int off = 1; off < 32; off <<= 1) {
                p0 += __shfl_xor(p0, off, 64);
                p1 += __shfl_xor(p1, off, 64);
                p2 += __shfl_xor(p2, off, 64);
                p3 += __shfl_xor(p3, off, 64);
            }
            if (q == 0 && row < n) h1[row] = make_float4(p0, p1, p2, p3);
        }
        return;
    }

    // ---- build role ----
    for (int i = t; i < NR; i += HB) hist[i] = 0;
    __syncthreads();

    int ds[EPT], sr[EPT];
    int base = b * EPB;
#pragma unroll
    for (int k = 0; k < 2; k++) {
        int idx = base + k * HB * 4 + t * 4;
        if (idx + 3 < e) {
            int4 d4 = *(const int4*)(dst + idx);
            int4 s4 = *(const int4*)(src + idx);
            ds[4 * k + 0] = d4.x; ds[4 * k + 1] = d4.y; ds[4 * k + 2] = d4.z; ds[4 * k + 3] = d4.w;
            sr[4 * k + 0] = s4.x; sr[4 * k + 1] = s4.y; sr[4 * k + 2] = s4.z; sr[4 * k + 3] = s4.w;
        } else {
#pragma unroll
            for (int j = 0; j < 4; j++) {
                int i2 = idx + j;
                if (i2 < e) { ds[4 * k + j] = dst[i2]; sr[4 * k + j] = src[i2]; }
                else ds[4 * k + j] = -1;
            }
        }
    }
#pragma unroll
    for (int k = 0; k < EPT; k++)
        if (ds[k] >= 0) atomicAdd(&hist[ds[k] / RNG], 1);
    __syncthreads();

    // wave-level inclusive scan over hist[0..NR) (NR=500, waves 0..7 of 8)
    {
        int lane = t & 63, wv = t >> 6;
        int v = (t < NR) ? hist[t] : 0;
        int sc = v;
#pragma unroll
        for (int off = 1; off < 64; off <<= 1) {
            int u = __shfl_up(sc, off, 64);
            if (lane >= off) sc += u;
        }
        if (lane == 63) wsum[wv] = sc;
        __syncthreads();
        if (t < 8) {
            int s = wsum[t];
#pragma unroll
            for (int off = 1; off < 8; off <<= 1) {
                int u = __shfl_up(s, off, 8);
                if (t >= off) s += u;
            }
            wsum[t] = s;  // inclusive wave sums
        }
        __syncthreads();
        int incl = sc + (wv ? wsum[wv - 1] : 0);
        if (t < NR) {
            int c = hist[t];
            int st = incl - c;
            start[t] = st;
            cur[t] = st;
            gbase[t] = c ? atomicAdd(&cursor[t * 16], c) : 0;
        }
        if (t == 0) start[NR] = wsum[7];
    }
    __syncthreads();

#pragma unroll
    for (int k = 0; k < EPT; k++) {
        if (ds[k] >= 0) {
            int bin = ds[k] / RNG;
            int p = atomicAdd(&cur[bin], 1);
            buf[p] = (sr[k] << 9) | (ds[k] - bin * RNG);
            bbin[p] = (short)bin;
        }
    }
    __syncthreads();

    int total = start[NR];
    for (int j = t; j < total; j += HB) {
        int bin = bbin[j];
        int g = gbase[bin] + (j - start[bin]);
        if (g < (bin + 1) * CAP) csrp[g] = buf[j];
    }
}

// ---------------- pass2: per-bin counting sort + dinv + g1 scale + splits ----------------

__global__ __launch_bounds__(1024) void k_sortbin(int* __restrict__ csrp,
                                                  const int* __restrict__ cursor,
                                                  int* __restrict__ split,
                                                  float* __restrict__ dinv,
                                                  const float4* __restrict__ h1,
                                                  float4* __restrict__ g1, int n) {
    __shared__ int deg[RNG];
    __shared__ int off[RNG];
    __shared__ int cur[RNG];
    __shared__ int wsum[8];
    __shared__ int qb[5];
    __shared__ int sbuf[SCAP];
    int t = threadIdx.x, b = blockIdx.x;
    int s0 = b * CAP;
    int cnt = cursor[b * 16] - s0;
    if (cnt < 0) cnt = 0; if (cnt > CAP) cnt = CAP;

    // single global pass: stage this thread's (up to 16) slots in registers
    int rg[16];
#pragma unroll
    for (int i = 0; i < 16; i++) {
        int j = t + i * 1024;
        rg[i] = (j < cnt) ? csrp[s0 + j] : -1;
    }

    for (int i = t; i < RNG; i += 1024) deg[i] = 0;
    __syncthreads();
#pragma unroll
    for (int i = 0; i < 16; i++)
        if (rg[i] >= 0) atomicAdd(&deg[rg[i] & 511], 1);
    __syncthreads();

    // wave-level inclusive scan over deg[0..RNG) (RNG=400 -> waves 0..6)
    {
        int lane = t & 63, wv = t >> 6;
        int v = (t < RNG) ? deg[t] : 0;
        int sc = v;
#pragma unroll
        for (int o = 1; o < 64; o <<= 1) {
            int u = __shfl_up(sc, o, 64);
            if (lane >= o) sc += u;
        }
        if (wv < 7 && lane == 63) wsum[wv] = sc;
        __syncthreads();
        if (t < 7) {
            int s = wsum[t];
#pragma unroll
            for (int o = 1; o < 8; o <<= 1) {
                int u = __shfl_up(s, o, 8);
                if (t >= o) s += u;
            }
            wsum[t] = s;
        }
        __syncthreads();
        if (t < RNG) off[t] = sc + (wv ? wsum[wv - 1] : 0);
    }
    __syncthreads();

    // 4-aligned quarter bases (local dst 0-99 / 100-199 / 200-299 / 300-399)
    if (t == 0) {
        int e0 = off[99], e1 = off[199], e2 = off[299], e3 = off[399];
        int b1 = (e0 + 3) & ~3;
        int b2 = (b1 + (e1 - e0) + 3) & ~3;
        int b3 = (b2 + (e2 - e1) + 3) & ~3;
        int b4 = (b3 + (e3 - e2) + 3) & ~3;
        qb[0] = 0; qb[1] = b1; qb[2] = b2; qb[3] = b3; qb[4] = b4;
        split[b * 4 + 0] = b1; split[b * 4 + 1] = b2;
        split[b * 4 + 2] = b3; split[b * 4 + 3] = b4;
    }
    __syncthreads();

    if (t < RNG) {
        int q = t / 100;
        int bstart = (q == 0) ? 0 : off[q * 100 - 1];
        cur[t] = (off[t] - deg[t]) - bstart + qb[q];
    }
    __syncthreads();

#pragma unroll
    for (int i = 0; i < 16; i++) {
        if (rg[i] >= 0) {
            int r = atomicAdd(&cur[rg[i] & 511], 1);
            if (r < SCAP) sbuf[r] = rg[i];
        }
    }
    __syncthreads();

    // pad gaps with sentinel edges: src=n (g[n]==0), loc=quarter start
    if (t < 12) {
        int q = t / 3, sl = t - q * 3;
        int eq = off[q * 100 + 99];
        int sq = (q == 0) ? 0 : off[q * 100 - 1];
        int realend = qb[q] + (eq - sq);
        int pos = realend + sl;
        if (pos < qb[q + 1] && pos < SCAP) sbuf[pos] = (n << 9) | (q * 100);
    }
    __syncthreads();

    int lim = qb[4]; if (lim > SCAP) lim = SCAP;
    for (int j = t; j < lim; j += 1024)
        csrp[s0 + j] = sbuf[j];

    int basen = b * RNG;
    for (int i = t; i < RNG; i += 1024) {
        int node = basen + i;
        if (node < n) {
            float dv = rsqrtf(1.0f + (float)deg[i]);
            dinv[node] = dv;
            float4 hv = h1[node];
            g1[node] = make_float4(dv * hv.x, dv * hv.y, dv * hv.z, dv * hv.w);
        }
    }
}

// ---------------- sorted-run aggregation: direct-atomic, quarter-bin blocks ----------------

#define PUSH4() { atomicAdd(&acc[cd * 5 + 0], a0); atomicAdd(&acc[cd * 5 + 1], a1); \
    atomicAdd(&acc[cd * 5 + 2], a2); atomicAdd(&acc[cd * 5 + 3], a3); }
#define EDGE4(di, gv) { int d_ = ((di) & 511) - qoff; \
    if (d_ != cd) { if (cd >= 0) PUSH4(); cd = d_; a0 = gv.x; a1 = gv.y; a2 = gv.z; a3 = gv.w; } \
    else { a0 += gv.x; a1 += gv.y; a2 += gv.z; a3 += gv.w; } }

// pipelined edge loop over this block's quarter range (4-aligned boundaries)
#define EDGELOOP4P() \
    int bin = b >> 2, qq = b & 3; \
    int qoff = qq * 100; \
    int s0 = bin * CAP; \
    int lo0 = qq ? split[bin * 4 + qq - 1] : 0; \
    int hi0 = split[bin * 4 + qq]; \
    int L = hi0 - lo0; \
    int per = (((L + 255) >> 8) + 3) & ~3; \
    int lo = s0 + lo0 + t * per; \
    int hi = lo + per; int eE = s0 + hi0; if (hi > eE) hi = eE; \
    int cd = -1; float a0 = 0, a1 = 0, a2 = 0, a3 = 0; \
    int4 pA, pB; \
    float4 gA0, gA1, gA2, gA3; \
    if (lo < hi) { \
        pA = *(const int4*)(csrp + lo); \
        gA0 = gin[(unsigned)pA.x >> 9]; gA1 = gin[(unsigned)pA.y >> 9]; \
        gA2 = gin[(unsigned)pA.z >> 9]; gA3 = gin[(unsigned)pA.w >> 9]; \
        int jB = lo + 4; \
        pB = *(const int4*)(csrp + ((jB < hi) ? jB : lo)); \
    } \
    for (int j = lo; j < hi; j += 4) { \
        int4 p = pA; \
        float4 g0 = gA0, g1v = gA1, g2v = gA2, g3v = gA3; \
        int jn = j + 4; \
        pA = pB; \
        if (jn < hi) { \
            gA0 = gin[(unsigned)pA.x >> 9]; gA1 = gin[(unsigned)pA.y >> 9]; \
            gA2 = gin[(unsigned)pA.z >> 9]; gA3 = gin[(unsigned)pA.w >> 9]; \
        } \
        int jB2 = j + 8; \
        pB = *(const int4*)(csrp + ((jB2 < hi) ? jB2 : lo)); \
        EDGE4(p.x, g0); \
        EDGE4(p.y, g1v); \
        EDGE4(p.z, g2v); \
        EDGE4(p.w, g3v); \
    } \
    if (cd >= 0) PUSH4(); \
    __syncthreads();

__global__ __launch_bounds__(256) void k_bagg44s(const int* __restrict__ csrp,
                                                 const int* __restrict__ split,
                                                 const float* __restrict__ dinv,
                                                 const float4* __restrict__ gin,
                                                 float4* __restrict__ gout,
                                                 const float* __restrict__ W,
                                                 const float* __restrict__ bv, int n) {
    __shared__ float acc[QBLK * 5];
    int t = threadIdx.x, b = blockIdx.x;
    for (int i = t; i < QBLK * 5; i += 256) acc[i] = 0.0f;
    __syncthreads();
    EDGELOOP4P();
    int basen = (b >> 2) * RNG + qoff;
    for (int i = t; i < QBLK; i += 256) {
        int node = basen + i;
        if (node >= n) continue;
        float4 gs = gin[node];
        float dv = dinv[node];
        float t0 = tanhf(dv * (gs.x + acc[i * 5 + 0]) + bv[0]);
        float t1 = tanhf(dv * (gs.y + acc[i * 5 + 1]) + bv[1]);
        float t2 = tanhf(dv * (gs.z + acc[i * 5 + 2]) + bv[2]);
        float t3 = tanhf(dv * (gs.w + acc[i * 5 + 3]) + bv[3]);
        float4 o;
        o.x = dv * (t0 * W[0] + t1 * W[4] + t2 * W[8]  + t3 * W[12]);
        o.y = dv * (t0 * W[1] + t1 * W[5] + t2 * W[9]  + t3 * W[13]);
        o.z = dv * (t0 * W[2] + t1 * W[6] + t2 * W[10] + t3 * W[14]);
        o.w = dv * (t0 * W[3] + t1 * W[7] + t2 * W[11] + t3 * W[15]);
        gout[node] = o;
    }
}

__global__ __launch_bounds__(256) void k_bagg42s(const int* __restrict__ csrp,
                                                 const int* __restrict__ split,
                                                 const float* __restrict__ dinv,
                                                 const float4* __restrict__ gin,
                                                 float2* __restrict__ gout,
                                                 const float* __restrict__ W,
                                                 const float* __restrict__ bv, int n) {
    __shared__ float acc[QBLK * 5];
    int t = threadIdx.x, b = blockIdx.x;
    for (int i = t; i < QBLK * 5; i += 256) acc[i] = 0.0f;
    __syncthreads();
    EDGELOOP4P();
    int basen = (b >> 2) * RNG + qoff;
    for (int i = t; i < QBLK; i += 256) {
        int node = basen + i;
        if (node >= n) continue;
        float4 gs = gin[node];
        float dv = dinv[node];
        float t0 = tanhf(dv * (gs.x + acc[i * 5 + 0]) + bv[0]);
        float t1 = tanhf(dv * (gs.y + acc[i * 5 + 1]) + bv[1]);
        float t2 = tanhf(dv * (gs.z + acc[i * 5 + 2]) + bv[2]);
        float t3 = tanhf(dv * (gs.w + acc[i * 5 + 3]) + bv[3]);
        float h0 = t0 * W[0] + t1 * W[2] + t2 * W[4] + t3 * W[6];
        float h1 = t0 * W[1] + t1 * W[3] + t2 * W[5] + t3 * W[7];
        gout[node] = make_float2(dv * h0, dv * h1);
    }
}

#define PUSH2() { atomicAdd(&acc[cd * 3 + 0], a0); atomicAdd(&acc[cd * 3 + 1], a1); }
#define EDGE2(di, gv) { int d_ = ((di) & 511) - qoff; \
    if (d_ != cd) { if (cd >= 0) PUSH2(); cd = d_; a0 = gv.x; a1 = gv.y; } \
    else { a0 += gv.x; a1 += gv.y; } }

__global__ __launch_bounds__(256) void k_bagg2outs(const int* __restrict__ csrp,
                                                   const int* __restrict__ split,
                                                   const float* __restrict__ dinv,
                                                   const float2* __restrict__ gin,
                                                   const float* __restrict__ b3,
                                                   const float* __restrict__ Wc,
                                                   const float* __restrict__ bc,
                                                   float* __restrict__ out,
                                                   float2* __restrict__ hout, int n) {
    __shared__ float acc[QBLK * 3];
    int t = threadIdx.x, b = blockIdx.x;
    for (int i = t; i < QBLK * 3; i += 256) acc[i] = 0.0f;
    __syncthreads();
    int bin = b >> 2, qq = b & 3;
    int qoff = qq * 100;
    int s0 = bin * CAP;
    int lo0 = qq ? split[bin * 4 + qq - 1] : 0;
    int hi0 = split[bin * 4 + qq];
    int L = hi0 - lo0;
    int per = (((L + 255) >> 8) + 3) & ~3;
    int lo = s0 + lo0 + t * per;
    int hi = lo + per; int eE = s0 + hi0; if (hi > eE) hi = eE;
    int cd = -1; float a0 = 0, a1 = 0;
    int4 pA, pB;
    float2 gA0, gA1, gA2, gA3;
    if (lo < hi) {
        pA = *(const int4*)(csrp + lo);
        gA0 = gin[(unsigned)pA.x >> 9]; gA1 = gin[(unsigned)pA.y >> 9];
        gA2 = gin[(unsigned)pA.z >> 9]; gA3 = gin[(unsigned)pA.w >> 9];
        int jB = lo + 4;
        pB = *(const int4*)(csrp + ((jB < hi) ? jB : lo));
    }
    for (int j = lo; j < hi; j += 4) {
        int4 p = pA;
        float2 g0 = gA0, g1v = gA1, g2v = gA2, g3v = gA3;
        int jn = j + 4;
        pA = pB;
        if (jn < hi) {
            gA0 = gin[(unsigned)pA.x >> 9]; gA1 = gin[(unsigned)pA.y >> 9];
            gA2 = gin[(unsigned)pA.z >> 9]; gA3 = gin[(unsigned)pA.w >> 9];
        }
        int jB2 = j + 8;
        pB = *(const int4*)(csrp + ((jB2 < hi) ? jB2 : lo));
        EDGE2(p.x, g0);
        EDGE2(p.y, g1v);
        EDGE2(p.z, g2v);
        EDGE2(p.w, g3v);
    }
    if (cd >= 0) PUSH2();
    __syncthreads();
    int basen = bin * RNG + qoff;
    for (int i = t; i < QBLK; i += 256) {
        int node = basen + i;
        if (node >= n) continue;
        float2 gs = gin[node];
        float dv = dinv[node];
        float t0 = tanhf(dv * (gs.x + acc[i * 3 + 0]) + b3[0]);
        float t1 = tanhf(dv * (gs.y + acc[i * 3 + 1]) + b3[1]);
        hout[node] = make_float2(t0, t1);
        float4* o = (float4*)(out + (size_t)node * 16);
#pragma unroll
        for (int q = 0; q < 4; q++) {
            float4 v;
            v.x = t0 * Wc[4 * q + 0] + t1 * Wc[16 + 4 * q + 0] + bc[4 * q + 0];
            v.y = t0 * Wc[4 * q + 1] + t1 * Wc[16 + 4 * q + 1] + bc[4 * q + 1];
            v.z = t0 * Wc[4 * q + 2] + t1 * Wc[16 + 4 * q + 2] + bc[4 * q + 2];
            v.w = t0 * Wc[4 * q + 3] + t1 * Wc[16 + 4 * q + 3] + bc[4 * q + 3];
            o[q] = v;
        }
    }
}

// ---------------- fallback path (round-1 proven, push atomics) ----------------

__global__ void k_count(const int* __restrict__ dst, int* __restrict__ cnt, int e) {
    int i = blockIdx.x * blockDim.x + threadIdx.x;
    if (i < e) atomicAdd(&cnt[dst[i]], 1);
}

__global__ void k_dinv_i(const int* __restrict__ cnt, float* __restrict__ dinv, int n) {
    int i = blockIdx.x * blockDim.x + threadIdx.x;
    if (i < n) dinv[i] = rsqrtf(1.0f + (float)cnt[i]);
}

__global__ void f_linear1(const float* __restrict__ x, const float* __restrict__ W1,
                          const float* __restrict__ dinv,
                          float* __restrict__ h, float* __restrict__ agg, int n) {
    int lane = threadIdx.x & 63;
    int wave = blockIdx.x * (blockDim.x >> 6) + (threadIdx.x >> 6);
    int nwaves = gridDim.x * (blockDim.x >> 6);
    float4 w0 = ((const float4*)W1)[2 * lane];
    float4 w1 = ((const float4*)W1)[2 * lane + 1];
    for (int row = wave; row < n; row += nwaves) {
        float2 xv = ((const float2*)(x + (size_t)row * 128))[lane];
        float p0 = xv.x * w0.x + xv.y * w1.x;
        float p1 = xv.x * w0.y + xv.y * w1.y;
        float p2 = xv.x * w0.z + xv.y * w1.z;
        float p3 = xv.x * w0.w + xv.y * w1.w;
#pragma unroll
        for (int off = 32; off; off >>= 1) {
            p0 += __shfl_xor(p0, off, 64);
            p1 += __shfl_xor(p1, off, 64);
            p2 += __shfl_xor(p2, off, 64);
            p3 += __shfl_xor(p3, off, 64);
        }
        if (lane == 0) {
            float dv = dinv[row]; float dv2 = dv * dv;
            ((float4*)h)[row] = make_float4(p0, p1, p2, p3);
            ((float4*)agg)[row] = make_float4(dv2 * p0, dv2 * p1, dv2 * p2, dv2 * p3);
        }
    }
}

__global__ void k_edge4(const int* __restrict__ src, const int* __restrict__ dst,
                        const float* __restrict__ dinv, const float* __restrict__ h,
                        float* __restrict__ agg, int e) {
    int i = blockIdx.x * blockDim.x + threadIdx.x;
    if (i >= e) return;
    int s = src[i], d = dst[i];
    float w = dinv[s] * dinv[d];
    float4 hv = ((const float4*)h)[s];
    float* a = agg + 4 * (size_t)d;
    unsafeAtomicAdd(a + 0, w * hv.x);
    unsafeAtomicAdd(a + 1, w * hv.y);
    unsafeAtomicAdd(a + 2, w * hv.z);
    unsafeAtomicAdd(a + 3, w * hv.w);
}

__global__ void k_edge2(const int* __restrict__ src, const int* __restrict__ dst,
                        const float* __restrict__ dinv, const float* __restrict__ h,
                        float* __restrict__ agg, int e) {
    int i = blockIdx.x * blockDim.x + threadIdx.x;
    if (i >= e) return;
    int s = src[i], d = dst[i];
    float w = dinv[s] * dinv[d];
    float2 hv = ((const float2*)h)[s];
    float* a = agg + 2 * (size_t)d;
    unsafeAtomicAdd(a + 0, w * hv.x);
    unsafeAtomicAdd(a + 1, w * hv.y);
}

__global__ void k_fin44(float* __restrict__ h, float* __restrict__ agg,
                        const float* __restrict__ dinv,
                        const float* __restrict__ W, const float* __restrict__ b, int n) {
    int i = blockIdx.x * blockDim.x + threadIdx.x;
    if (i >= n) return;
    float4 a = ((const float4*)agg)[i];
    float t0 = tanhf(a.x + b[0]);
    float t1 = tanhf(a.y + b[1]);
    float t2 = tanhf(a.z + b[2]);
    float t3 = tanhf(a.w + b[3]);
    float hn[4];
#pragma unroll
    for (int k = 0; k < 4; k++)
        hn[k] = t0 * W[k] + t1 * W[4 + k] + t2 * W[8 + k] + t3 * W[12 + k];
    float dv = dinv[i], dv2 = dv * dv;
    ((float4*)h)[i] = make_float4(hn[0], hn[1], hn[2], hn[3]);
    ((float4*)agg)[i] = make_float4(dv2 * hn[0], dv2 * hn[1], dv2 * hn[2], dv2 * hn[3]);
}

__global__ void k_fin42(const float* __restrict__ agg, float* __restrict__ h3,
                        float* __restrict__ agg3, const float* __restrict__ dinv,
                        const float* __restrict__ W, const float* __restrict__ b, int n) {
    int i = blockIdx.x * blockDim.x + threadIdx.x;
    if (i >= n) return;
    float4 a = ((const float4*)agg)[i];
    float t0 = tanhf(a.x + b[0]);
    float t1 = tanhf(a.y + b[1]);
    float t2 = tanhf(a.z + b[2]);
    float t3 = tanhf(a.w + b[3]);
    float h0 = t0 * W[0] + t1 * W[2] + t2 * W[4] + t3 * W[6];
    float h1 = t0 * W[1] + t1 * W[3] + t2 * W[5] + t3 * W[7];
    float dv = dinv[i], dv2 = dv * dv;
    ((float2*)h3)[i] = make_float2(h0, h1);
    ((float2*)agg3)[i] = make_float2(dv2 * h0, dv2 * h1);
}

__global__ void k_final_old(const float* __restrict__ agg3,
                            const float* __restrict__ Wc, const float* __restrict__ b3,
                            const float* __restrict__ bc,
                            float* __restrict__ out, float* __restrict__ hout, int n) {
    int i = blockIdx.x * blockDim.x + threadIdx.x;
    if (i >= n) return;
    float2 a = ((const float2*)agg3)[i];
    float t0 = tanhf(a.x + b3[0]);
    float t1 = tanhf(a.y + b3[1]);
    ((float2*)hout)[i] = make_float2(t0, t1);
    float4* o = (float4*)(out + (size_t)i * 16);
#pragma unroll
    for (int q = 0; q < 4; q++) {
        float4 v;
        v.x = t0 * Wc[4 * q + 0] + t1 * Wc[16 + 4 * q + 0] + bc[4 * q + 0];
        v.y = t0 * Wc[4 * q + 1] + t1 * Wc[16 + 4 * q + 1] + bc[4 * q + 1];
        v.z = t0 * Wc[4 * q + 2] + t1 * Wc[16 + 4 * q + 2] + bc[4 * q + 2];
        v.w = t0 * Wc[4 * q + 3] + t1 * Wc[16 + 4 * q + 3] + bc[4 * q + 3];
        o[q] = v;
    }
}

// ---------------- launcher ----------------

extern "C" void kernel_launch(void* const* d_in, const int* in_sizes, int n_in,
                              void* d_out, int out_size, void* d_ws, size_t ws_size,
                              hipStream_t stream) {
    const float* x   = (const float*)d_in[0];
    const float* W1  = (const float*)d_in[1];
    const float* b1  = (const float*)d_in[2];
    const float* W2  = (const float*)d_in[3];
    const float* b2  = (const float*)d_in[4];
    const float* W3  = (const float*)d_in[5];
    const float* b3  = (const float*)d_in[6];
    const float* Wc  = (const float*)d_in[7];
    const float* bc  = (const float*)d_in[8];
    const int* eidx  = (const int*)d_in[9];

    const int n = in_sizes[0] / 128;   // 200000
    const int e = in_sizes[9] / 2;     // 6400000
    const int* src = eidx;
    const int* dst = eidx + e;

    float* out_c = (float*)d_out;                   // [n,16]
    float* out_h = (float*)d_out + 16 * (size_t)n;  // [n,2]

    const int B = 256;
    const int gn = (n + B - 1) / B;
    const int ge = (e + B - 1) / B;
    const int nbE = (e + EPB - 1) / EPB;            // build blocks
    const int nbL = (n + LINR - 1) / LINR;          // lin-role blocks

    size_t nP = ((size_t)(n + 4) + 3) & ~(size_t)3; // +1 zeroed sentinel row

    // fast-path workspace layout (csrp has 4096-int slack for tail overreads)
    int* csrp    = (int*)d_ws;                         // NR*CAP + 4096
    int* cursor  = csrp + (size_t)NR * CAP + 4096;     // NR*16
    int* split   = cursor + NR * 16;                   // NR*4
    float* dinv  = (float*)(split + NR * 4);
    float* h1    = dinv + nP;                 // 4nP
    float* g1    = h1 + 4 * nP;               // 4nP
    float* g2    = g1 + 4 * nP;               // 4nP
    float* g3    = g2 + 4 * nP;               // 2nP
    size_t need  = (size_t)((char*)(g3 + 2 * nP) - (char*)d_ws);

    bool fast = (ws_size >= need) && (n <= NR * RNG) && (n < (1 << 18));

    if (fast) {
        k_initcur<<<(NR + 255) / 256, 256, 0, stream>>>(cursor, g1, g2, g3, n);
        k_build_lin<<<nbE + nbL, HB, 0, stream>>>(src, dst, cursor, csrp,
                                                  x, W1, (float4*)h1, e, n, nbE);
        k_sortbin<<<NR, 1024, 0, stream>>>(csrp, cursor, split, dinv,
                                           (const float4*)h1, (float4*)g1, n);

        k_bagg44s<<<NR * 4, 256, 0, stream>>>(csrp, split, dinv, (const float4*)g1,
                                              (float4*)g2, W2, b1, n);
        k_bagg42s<<<NR * 4, 256, 0, stream>>>(csrp, split, dinv, (const float4*)g2,
                                              (float2*)g3, W3, b2, n);
        k_bagg2outs<<<NR * 4, 256, 0, stream>>>(csrp, split, dinv, (const float2*)g3,
                                                b3, Wc, bc, out_c, (float2*)out_h, n);
    } else {
        // fallback: push-atomic path (~11MB ws)
        int* fcnt   = (int*)d_ws;
        float* fdnv = (float*)d_ws + nP;
        float* h    = fdnv + nP;
        float* agg  = h + 4 * nP;
        float* h3   = agg + 4 * nP;
        float* agg3 = h3 + 2 * nP;

        hipMemsetAsync(fcnt, 0, (size_t)n * sizeof(int), stream);
        k_count<<<ge, B, 0, stream>>>(dst, fcnt, e);
        k_dinv_i<<<gn, B, 0, stream>>>(fcnt, fdnv, n);
        f_linear1<<<(n + 3) / 4, B, 0, stream>>>(x, W1, fdnv, h, agg, n);
        k_edge4<<<ge, B, 0, stream>>>(src, dst, fdnv, h, agg, e);
        k_fin44<<<gn, B, 0, stream>>>(h, agg, fdnv, W2, b1, n);
        k_edge4<<<ge, B, 0, stream>>>(src, dst, fdnv, h, agg, e);
        k_fin42<<<gn, B, 0, stream>>>(agg, h3, agg3, fdnv, W3, b2, n);
        k_edge2<<<ge, B, 0, stream>>>(src, dst, fdnv, h3, agg3, e);
        k_final_old<<<gn, B, 0, stream>>>(agg3, Wc, b3, bc, out_c, (float*)out_h, n);
    }
}

// Round 9
// 347.506 us; speedup vs baseline: 1.0637x; 1.0637x over previous
//
#include <hip/hip_runtime.h>
#include <math.h>

// GCN 3-layer + classifier — round 19.
// Round-18 discriminating experiment: HB=512 made build_lin WORSE (88->92us,
// WRITE_SIZE 48->69MB) -> write-coalescing + cursor-chain favor FEWER, LARGER
// build blocks. Round 19 runs that mechanism forward:
//  (a) EPT=16 -> EPB=16384 (391 blocks): per-bin runs ~33 edges (132B) for
//      better write coalescing; cursor RMW chains halved.
//  (b) writeout is wave-per-bin (wave copies start[bin]..start[bin+1] ->
//      gbase[bin]+..): wave-coherent stores, bbin[] eliminated (LDS 73.6KB,
//      2 blocks/CU).
// Base: round-17 (353us, passed) everywhere else.
//
// Math identity: agg[d] = dinv[d]*( g[d] + sum_{in} g[s] ),  g = dinv*h.

#define NR 500
#define RNG 400
#define CAP 16384            // slots per bin (expect ~12800 +- 113); = 16*1024
#define HB 1024              // build threads
#define EPT 16               // build edges per thread
#define EPB (HB * EPT)       // 16384 edges per build block
#define SCAP 14348           // sortbin LDS buffer (mean+13 sigma, 4-aligned)
#define QBLK 100             // dst nodes per bagg block (RNG/4)
#define LINR 128             // rows per lin-role block

// ---------------- init: cursors + zero sentinel g-rows ----------------

__global__ void k_initcur(int* __restrict__ cursor, float* __restrict__ g1,
                          float* __restrict__ g2, float* __restrict__ g3, int n) {
    int t = blockIdx.x * blockDim.x + threadIdx.x;
    if (t < NR) cursor[t * 16] = t * CAP;
    if (t < 4) g1[4 * (size_t)n + t] = 0.0f;
    if (t >= 4 && t < 8) g2[4 * (size_t)n + (t - 4)] = 0.0f;
    if (t >= 8 && t < 10) g3[2 * (size_t)n + (t - 8)] = 0.0f;
}

// ---------------- build (bin by dst/400) + fused h1 = x @ W1 ----------------

__global__ __launch_bounds__(HB) void k_build_lin(const int* __restrict__ src,
                                                  const int* __restrict__ dst,
                                                  int* __restrict__ cursor,
                                                  int* __restrict__ csrp,
                                                  const float* __restrict__ x,
                                                  const float* __restrict__ W1,
                                                  float4* __restrict__ h1,
                                                  int e, int n, int nBuild) {
    __shared__ int hist[NR];
    __shared__ int start[NR + 1];
    __shared__ int gbase[NR];
    __shared__ int cur[NR];
    __shared__ int wsum[16];
    __shared__ int buf[EPB];     // 64KB

    int t = threadIdx.x;
    int b = blockIdx.x;

    if (b >= nBuild) {
        // ---- lin role: h1[row] = x[row,:] @ W1, 32 threads per row ----
        int row0 = (b - nBuild) * LINR;
        int q = t & 31, r = t >> 5;          // k-slice q (4 floats), row-group r
        float4 w0 = ((const float4*)W1)[q * 4 + 0];
        float4 w1 = ((const float4*)W1)[q * 4 + 1];
        float4 w2 = ((const float4*)W1)[q * 4 + 2];
        float4 w3 = ((const float4*)W1)[q * 4 + 3];
#pragma unroll
        for (int rr = 0; rr < 4; rr++) {
            int row = row0 + rr * 32 + r;
            int rowc = (row < n) ? row : (n - 1);   // clamp (no divergent break)
            float4 xv = ((const float4*)(x + (size_t)rowc * 128))[q];
            float p0 = xv.x * w0.x + xv.y * w1.x + xv.z * w2.x + xv.w * w3.x;
            float p1 = xv.x * w0.y + xv.y * w1.y + xv.z * w2.y + xv.w * w3.y;
            float p2 = xv.x * w0.z + xv.y * w1.z + xv.z * w2.z + xv.w * w3.z;
            float p3 = xv.x * w0.w + xv.y * w1.w + xv.z * w2.w + xv.w * w3.w;
#pragma unroll
            for (int off = 1; off < 32; off <<= 1) {
                p0 += __shfl_xor(p0, off, 64);
                p1 += __shfl_xor(p1, off, 64);
                p2 += __shfl_xor(p2, off, 64);
                p3 += __shfl_xor(p3, off, 64);
            }
            if (q == 0 && row < n) h1[row] = make_float4(p0, p1, p2, p3);
        }
        return;
    }

    // ---- build role ----
    for (int i = t; i < NR; i += HB) hist[i] = 0;
    __syncthreads();

    int ds[EPT], sr[EPT];
    int base = b * EPB;
#pragma unroll
    for (int k = 0; k < 4; k++) {
        int idx = base + k * HB * 4 + t * 4;
        if (idx + 3 < e) {
            int4 d4 = *(const int4*)(dst + idx);
            int4 s4 = *(const int4*)(src + idx);
            ds[4 * k + 0] = d4.x; ds[4 * k + 1] = d4.y; ds[4 * k + 2] = d4.z; ds[4 * k + 3] = d4.w;
            sr[4 * k + 0] = s4.x; sr[4 * k + 1] = s4.y; sr[4 * k + 2] = s4.z; sr[4 * k + 3] = s4.w;
        } else {
#pragma unroll
            for (int j = 0; j < 4; j++) {
                int i2 = idx + j;
                if (i2 < e) { ds[4 * k + j] = dst[i2]; sr[4 * k + j] = src[i2]; }
                else ds[4 * k + j] = -1;
            }
        }
    }
#pragma unroll
    for (int k = 0; k < EPT; k++)
        if (ds[k] >= 0) atomicAdd(&hist[ds[k] / RNG], 1);
    __syncthreads();

    // wave-level inclusive scan over hist[0..NR) (NR=500 -> waves 0..7 of 16)
    {
        int lane = t & 63, wv = t >> 6;
        int v = (t < NR) ? hist[t] : 0;
        int sc = v;
#pragma unroll
        for (int off = 1; off < 64; off <<= 1) {
            int u = __shfl_up(sc, off, 64);
            if (lane >= off) sc += u;
        }
        if (lane == 63) wsum[wv] = sc;
        __syncthreads();
        if (t < 16) {
            int s = wsum[t];
#pragma unroll
            for (int off = 1; off < 16; off <<= 1) {
                int u = __shfl_up(s, off, 16);
                if (t >= off) s += u;
            }
            wsum[t] = s;  // inclusive wave sums
        }
        __syncthreads();
        int incl = sc + (wv ? wsum[wv - 1] : 0);
        if (t < NR) {
            int c = hist[t];
            int st = incl - c;
            start[t] = st;
            cur[t] = st;
            gbase[t] = c ? atomicAdd(&cursor[t * 16], c) : 0;
        }
        if (t == 0) start[NR] = wsum[15];
    }
    __syncthreads();

#pragma unroll
    for (int k = 0; k < EPT; k++) {
        if (ds[k] >= 0) {
            int bin = ds[k] / RNG;
            int p = atomicAdd(&cur[bin], 1);
            buf[p] = (sr[k] << 9) | (ds[k] - bin * RNG);
        }
    }
    __syncthreads();

    // wave-per-bin writeout: wave wv handles bins wv, wv+16, ... (wave-coherent runs)
    {
        int lane = t & 63, wv = t >> 6;
        for (int bin = wv; bin < NR; bin += 16) {
            int st = start[bin], en = start[bin + 1];
            int g0 = gbase[bin];
            int cap = (bin + 1) * CAP;
            for (int j = st + lane; j < en; j += 64) {
                int g = g0 + (j - st);
                if (g < cap) csrp[g] = buf[j];
            }
        }
    }
}

// ---------------- pass2: per-bin counting sort + dinv + g1 scale + splits ----------------

__global__ __launch_bounds__(1024) void k_sortbin(int* __restrict__ csrp,
                                                  const int* __restrict__ cursor,
                                                  int* __restrict__ split,
                                                  float* __restrict__ dinv,
                                                  const float4* __restrict__ h1,
                                                  float4* __restrict__ g1, int n) {
    __shared__ int deg[RNG];
    __shared__ int off[RNG];
    __shared__ int cur[RNG];
    __shared__ int wsum[8];
    __shared__ int qb[5];
    __shared__ int sbuf[SCAP];
    int t = threadIdx.x, b = blockIdx.x;
    int s0 = b * CAP;
    int cnt = cursor[b * 16] - s0;
    if (cnt < 0) cnt = 0; if (cnt > CAP) cnt = CAP;

    // single global pass: stage this thread's (up to 16) slots in registers
    int rg[16];
#pragma unroll
    for (int i = 0; i < 16; i++) {
        int j = t + i * 1024;
        rg[i] = (j < cnt) ? csrp[s0 + j] : -1;
    }

    for (int i = t; i < RNG; i += 1024) deg[i] = 0;
    __syncthreads();
#pragma unroll
    for (int i = 0; i < 16; i++)
        if (rg[i] >= 0) atomicAdd(&deg[rg[i] & 511], 1);
    __syncthreads();

    // wave-level inclusive scan over deg[0..RNG) (RNG=400 -> waves 0..6)
    {
        int lane = t & 63, wv = t >> 6;
        int v = (t < RNG) ? deg[t] : 0;
        int sc = v;
#pragma unroll
        for (int o = 1; o < 64; o <<= 1) {
            int u = __shfl_up(sc, o, 64);
            if (lane >= o) sc += u;
        }
        if (wv < 7 && lane == 63) wsum[wv] = sc;
        __syncthreads();
        if (t < 7) {
            int s = wsum[t];
#pragma unroll
            for (int o = 1; o < 8; o <<= 1) {
                int u = __shfl_up(s, o, 8);
                if (t >= o) s += u;
            }
            wsum[t] = s;
        }
        __syncthreads();
        if (t < RNG) off[t] = sc + (wv ? wsum[wv - 1] : 0);
    }
    __syncthreads();

    // 4-aligned quarter bases (local dst 0-99 / 100-199 / 200-299 / 300-399)
    if (t == 0) {
        int e0 = off[99], e1 = off[199], e2 = off[299], e3 = off[399];
        int b1 = (e0 + 3) & ~3;
        int b2 = (b1 + (e1 - e0) + 3) & ~3;
        int b3 = (b2 + (e2 - e1) + 3) & ~3;
        int b4 = (b3 + (e3 - e2) + 3) & ~3;
        qb[0] = 0; qb[1] = b1; qb[2] = b2; qb[3] = b3; qb[4] = b4;
        split[b * 4 + 0] = b1; split[b * 4 + 1] = b2;
        split[b * 4 + 2] = b3; split[b * 4 + 3] = b4;
    }
    __syncthreads();

    if (t < RNG) {
        int q = t / 100;
        int bstart = (q == 0) ? 0 : off[q * 100 - 1];
        cur[t] = (off[t] - deg[t]) - bstart + qb[q];
    }
    __syncthreads();

#pragma unroll
    for (int i = 0; i < 16; i++) {
        if (rg[i] >= 0) {
            int r = atomicAdd(&cur[rg[i] & 511], 1);
            if (r < SCAP) sbuf[r] = rg[i];
        }
    }
    __syncthreads();

    // pad gaps with sentinel edges: src=n (g[n]==0), loc=quarter start
    if (t < 12) {
        int q = t / 3, sl = t - q * 3;
        int eq = off[q * 100 + 99];
        int sq = (q == 0) ? 0 : off[q * 100 - 1];
        int realend = qb[q] + (eq - sq);
        int pos = realend + sl;
        if (pos < qb[q + 1] && pos < SCAP) sbuf[pos] = (n << 9) | (q * 100);
    }
    __syncthreads();

    int lim = qb[4]; if (lim > SCAP) lim = SCAP;
    for (int j = t; j < lim; j += 1024)
        csrp[s0 + j] = sbuf[j];

    int basen = b * RNG;
    for (int i = t; i < RNG; i += 1024) {
        int node = basen + i;
        if (node < n) {
            float dv = rsqrtf(1.0f + (float)deg[i]);
            dinv[node] = dv;
            float4 hv = h1[node];
            g1[node] = make_float4(dv * hv.x, dv * hv.y, dv * hv.z, dv * hv.w);
        }
    }
}

// ---------------- sorted-run aggregation: direct-atomic, quarter-bin blocks ----------------

#define PUSH4() { atomicAdd(&acc[cd * 5 + 0], a0); atomicAdd(&acc[cd * 5 + 1], a1); \
    atomicAdd(&acc[cd * 5 + 2], a2); atomicAdd(&acc[cd * 5 + 3], a3); }
#define EDGE4(di, gv) { int d_ = ((di) & 511) - qoff; \
    if (d_ != cd) { if (cd >= 0) PUSH4(); cd = d_; a0 = gv.x; a1 = gv.y; a2 = gv.z; a3 = gv.w; } \
    else { a0 += gv.x; a1 += gv.y; a2 += gv.z; a3 += gv.w; } }

// pipelined edge loop over this block's quarter range (4-aligned boundaries)
#define EDGELOOP4P() \
    int bin = b >> 2, qq = b & 3; \
    int qoff = qq * 100; \
    int s0 = bin * CAP; \
    int lo0 = qq ? split[bin * 4 + qq - 1] : 0; \
    int hi0 = split[bin * 4 + qq]; \
    int L = hi0 - lo0; \
    int per = (((L + 255) >> 8) + 3) & ~3; \
    int lo = s0 + lo0 + t * per; \
    int hi = lo + per; int eE = s0 + hi0; if (hi > eE) hi = eE; \
    int cd = -1; float a0 = 0, a1 = 0, a2 = 0, a3 = 0; \
    int4 pA, pB; \
    float4 gA0, gA1, gA2, gA3; \
    if (lo < hi) { \
        pA = *(const int4*)(csrp + lo); \
        gA0 = gin[(unsigned)pA.x >> 9]; gA1 = gin[(unsigned)pA.y >> 9]; \
        gA2 = gin[(unsigned)pA.z >> 9]; gA3 = gin[(unsigned)pA.w >> 9]; \
        int jB = lo + 4; \
        pB = *(const int4*)(csrp + ((jB < hi) ? jB : lo)); \
    } \
    for (int j = lo; j < hi; j += 4) { \
        int4 p = pA; \
        float4 g0 = gA0, g1v = gA1, g2v = gA2, g3v = gA3; \
        int jn = j + 4; \
        pA = pB; \
        if (jn < hi) { \
            gA0 = gin[(unsigned)pA.x >> 9]; gA1 = gin[(unsigned)pA.y >> 9]; \
            gA2 = gin[(unsigned)pA.z >> 9]; gA3 = gin[(unsigned)pA.w >> 9]; \
        } \
        int jB2 = j + 8; \
        pB = *(const int4*)(csrp + ((jB2 < hi) ? jB2 : lo)); \
        EDGE4(p.x, g0); \
        EDGE4(p.y, g1v); \
        EDGE4(p.z, g2v); \
        EDGE4(p.w, g3v); \
    } \
    if (cd >= 0) PUSH4(); \
    __syncthreads();

__global__ __launch_bounds__(256) void k_bagg44s(const int* __restrict__ csrp,
                                                 const int* __restrict__ split,
                                                 const float* __restrict__ dinv,
                                                 const float4* __restrict__ gin,
                                                 float4* __restrict__ gout,
                                                 const float* __restrict__ W,
                                                 const float* __restrict__ bv, int n) {
    __shared__ float acc[QBLK * 5];
    int t = threadIdx.x, b = blockIdx.x;
    for (int i = t; i < QBLK * 5; i += 256) acc[i] = 0.0f;
    __syncthreads();
    EDGELOOP4P();
    int basen = (b >> 2) * RNG + qoff;
    for (int i = t; i < QBLK; i += 256) {
        int node = basen + i;
        if (node >= n) continue;
        float4 gs = gin[node];
        float dv = dinv[node];
        float t0 = tanhf(dv * (gs.x + acc[i * 5 + 0]) + bv[0]);
        float t1 = tanhf(dv * (gs.y + acc[i * 5 + 1]) + bv[1]);
        float t2 = tanhf(dv * (gs.z + acc[i * 5 + 2]) + bv[2]);
        float t3 = tanhf(dv * (gs.w + acc[i * 5 + 3]) + bv[3]);
        float4 o;
        o.x = dv * (t0 * W[0] + t1 * W[4] + t2 * W[8]  + t3 * W[12]);
        o.y = dv * (t0 * W[1] + t1 * W[5] + t2 * W[9]  + t3 * W[13]);
        o.z = dv * (t0 * W[2] + t1 * W[6] + t2 * W[10] + t3 * W[14]);
        o.w = dv * (t0 * W[3] + t1 * W[7] + t2 * W[11] + t3 * W[15]);
        gout[node] = o;
    }
}

__global__ __launch_bounds__(256) void k_bagg42s(const int* __restrict__ csrp,
                                                 const int* __restrict__ split,
                                                 const float* __restrict__ dinv,
                                                 const float4* __restrict__ gin,
                                                 float2* __restrict__ gout,
                                                 const float* __restrict__ W,
                                                 const float* __restrict__ bv, int n) {
    __shared__ float acc[QBLK * 5];
    int t = threadIdx.x, b = blockIdx.x;
    for (int i = t; i < QBLK * 5; i += 256) acc[i] = 0.0f;
    __syncthreads();
    EDGELOOP4P();
    int basen = (b >> 2) * RNG + qoff;
    for (int i = t; i < QBLK; i += 256) {
        int node = basen + i;
        if (node >= n) continue;
        float4 gs = gin[node];
        float dv = dinv[node];
        float t0 = tanhf(dv * (gs.x + acc[i * 5 + 0]) + bv[0]);
        float t1 = tanhf(dv * (gs.y + acc[i * 5 + 1]) + bv[1]);
        float t2 = tanhf(dv * (gs.z + acc[i * 5 + 2]) + bv[2]);
        float t3 = tanhf(dv * (gs.w + acc[i * 5 + 3]) + bv[3]);
        float h0 = t0 * W[0] + t1 * W[2] + t2 * W[4] + t3 * W[6];
        float h1 = t0 * W[1] + t1 * W[3] + t2 * W[5] + t3 * W[7];
        gout[node] = make_float2(dv * h0, dv * h1);
    }
}

#define PUSH2() { atomicAdd(&acc[cd * 3 + 0], a0); atomicAdd(&acc[cd * 3 + 1], a1); }
#define EDGE2(di, gv) { int d_ = ((di) & 511) - qoff; \
    if (d_ != cd) { if (cd >= 0) PUSH2(); cd = d_; a0 = gv.x; a1 = gv.y; } \
    else { a0 += gv.x; a1 += gv.y; } }

__global__ __launch_bounds__(256) void k_bagg2outs(const int* __restrict__ csrp,
                                                   const int* __restrict__ split,
                                                   const float* __restrict__ dinv,
                                                   const float2* __restrict__ gin,
                                                   const float* __restrict__ b3,
                                                   const float* __restrict__ Wc,
                                                   const float* __restrict__ bc,
                                                   float* __restrict__ out,
                                                   float2* __restrict__ hout, int n) {
    __shared__ float acc[QBLK * 3];
    int t = threadIdx.x, b = blockIdx.x;
    for (int i = t; i < QBLK * 3; i += 256) acc[i] = 0.0f;
    __syncthreads();
    int bin = b >> 2, qq = b & 3;
    int qoff = qq * 100;
    int s0 = bin * CAP;
    int lo0 = qq ? split[bin * 4 + qq - 1] : 0;
    int hi0 = split[bin * 4 + qq];
    int L = hi0 - lo0;
    int per = (((L + 255) >> 8) + 3) & ~3;
    int lo = s0 + lo0 + t * per;
    int hi = lo + per; int eE = s0 + hi0; if (hi > eE) hi = eE;
    int cd = -1; float a0 = 0, a1 = 0;
    int4 pA, pB;
    float2 gA0, gA1, gA2, gA3;
    if (lo < hi) {
        pA = *(const int4*)(csrp + lo);
        gA0 = gin[(unsigned)pA.x >> 9]; gA1 = gin[(unsigned)pA.y >> 9];
        gA2 = gin[(unsigned)pA.z >> 9]; gA3 = gin[(unsigned)pA.w >> 9];
        int jB = lo + 4;
        pB = *(const int4*)(csrp + ((jB < hi) ? jB : lo));
    }
    for (int j = lo; j < hi; j += 4) {
        int4 p = pA;
        float2 g0 = gA0, g1v = gA1, g2v = gA2, g3v = gA3;
        int jn = j + 4;
        pA = pB;
        if (jn < hi) {
            gA0 = gin[(unsigned)pA.x >> 9]; gA1 = gin[(unsigned)pA.y >> 9];
            gA2 = gin[(unsigned)pA.z >> 9]; gA3 = gin[(unsigned)pA.w >> 9];
        }
        int jB2 = j + 8;
        pB = *(const int4*)(csrp + ((jB2 < hi) ? jB2 : lo));
        EDGE2(p.x, g0);
        EDGE2(p.y, g1v);
        EDGE2(p.z, g2v);
        EDGE2(p.w, g3v);
    }
    if (cd >= 0) PUSH2();
    __syncthreads();
    int basen = bin * RNG + qoff;
    for (int i = t; i < QBLK; i += 256) {
        int node = basen + i;
        if (node >= n) continue;
        float2 gs = gin[node];
        float dv = dinv[node];
        float t0 = tanhf(dv * (gs.x + acc[i * 3 + 0]) + b3[0]);
        float t1 = tanhf(dv * (gs.y + acc[i * 3 + 1]) + b3[1]);
        hout[node] = make_float2(t0, t1);
        float4* o = (float4*)(out + (size_t)node * 16);
#pragma unroll
        for (int q = 0; q < 4; q++) {
            float4 v;
            v.x = t0 * Wc[4 * q + 0] + t1 * Wc[16 + 4 * q + 0] + bc[4 * q + 0];
            v.y = t0 * Wc[4 * q + 1] + t1 * Wc[16 + 4 * q + 1] + bc[4 * q + 1];
            v.z = t0 * Wc[4 * q + 2] + t1 * Wc[16 + 4 * q + 2] + bc[4 * q + 2];
            v.w = t0 * Wc[4 * q + 3] + t1 * Wc[16 + 4 * q + 3] + bc[4 * q + 3];
            o[q] = v;
        }
    }
}

// ---------------- fallback path (round-1 proven, push atomics) ----------------

__global__ void k_count(const int* __restrict__ dst, int* __restrict__ cnt, int e) {
    int i = blockIdx.x * blockDim.x + threadIdx.x;
    if (i < e) atomicAdd(&cnt[dst[i]], 1);
}

__global__ void k_dinv_i(const int* __restrict__ cnt, float* __restrict__ dinv, int n) {
    int i = blockIdx.x * blockDim.x + threadIdx.x;
    if (i < n) dinv[i] = rsqrtf(1.0f + (float)cnt[i]);
}

__global__ void f_linear1(const float* __restrict__ x, const float* __restrict__ W1,
                          const float* __restrict__ dinv,
                          float* __restrict__ h, float* __restrict__ agg, int n) {
    int lane = threadIdx.x & 63;
    int wave = blockIdx.x * (blockDim.x >> 6) + (threadIdx.x >> 6);
    int nwaves = gridDim.x * (blockDim.x >> 6);
    float4 w0 = ((const float4*)W1)[2 * lane];
    float4 w1 = ((const float4*)W1)[2 * lane + 1];
    for (int row = wave; row < n; row += nwaves) {
        float2 xv = ((const float2*)(x + (size_t)row * 128))[lane];
        float p0 = xv.x * w0.x + xv.y * w1.x;
        float p1 = xv.x * w0.y + xv.y * w1.y;
        float p2 = xv.x * w0.z + xv.y * w1.z;
        float p3 = xv.x * w0.w + xv.y * w1.w;
#pragma unroll
        for (int off = 32; off; off >>= 1) {
            p0 += __shfl_xor(p0, off, 64);
            p1 += __shfl_xor(p1, off, 64);
            p2 += __shfl_xor(p2, off, 64);
            p3 += __shfl_xor(p3, off, 64);
        }
        if (lane == 0) {
            float dv = dinv[row]; float dv2 = dv * dv;
            ((float4*)h)[row] = make_float4(p0, p1, p2, p3);
            ((float4*)agg)[row] = make_float4(dv2 * p0, dv2 * p1, dv2 * p2, dv2 * p3);
        }
    }
}

__global__ void k_edge4(const int* __restrict__ src, const int* __restrict__ dst,
                        const float* __restrict__ dinv, const float* __restrict__ h,
                        float* __restrict__ agg, int e) {
    int i = blockIdx.x * blockDim.x + threadIdx.x;
    if (i >= e) return;
    int s = src[i], d = dst[i];
    float w = dinv[s] * dinv[d];
    float4 hv = ((const float4*)h)[s];
    float* a = agg + 4 * (size_t)d;
    unsafeAtomicAdd(a + 0, w * hv.x);
    unsafeAtomicAdd(a + 1, w * hv.y);
    unsafeAtomicAdd(a + 2, w * hv.z);
    unsafeAtomicAdd(a + 3, w * hv.w);
}

__global__ void k_edge2(const int* __restrict__ src, const int* __restrict__ dst,
                        const float* __restrict__ dinv, const float* __restrict__ h,
                        float* __restrict__ agg, int e) {
    int i = blockIdx.x * blockDim.x + threadIdx.x;
    if (i >= e) return;
    int s = src[i], d = dst[i];
    float w = dinv[s] * dinv[d];
    float2 hv = ((const float2*)h)[s];
    float* a = agg + 2 * (size_t)d;
    unsafeAtomicAdd(a + 0, w * hv.x);
    unsafeAtomicAdd(a + 1, w * hv.y);
}

__global__ void k_fin44(float* __restrict__ h, float* __restrict__ agg,
                        const float* __restrict__ dinv,
                        const float* __restrict__ W, const float* __restrict__ b, int n) {
    int i = blockIdx.x * blockDim.x + threadIdx.x;
    if (i >= n) return;
    float4 a = ((const float4*)agg)[i];
    float t0 = tanhf(a.x + b[0]);
    float t1 = tanhf(a.y + b[1]);
    float t2 = tanhf(a.z + b[2]);
    float t3 = tanhf(a.w + b[3]);
    float hn[4];
#pragma unroll
    for (int k = 0; k < 4; k++)
        hn[k] = t0 * W[k] + t1 * W[4 + k] + t2 * W[8 + k] + t3 * W[12 + k];
    float dv = dinv[i], dv2 = dv * dv;
    ((float4*)h)[i] = make_float4(hn[0], hn[1], hn[2], hn[3]);
    ((float4*)agg)[i] = make_float4(dv2 * hn[0], dv2 * hn[1], dv2 * hn[2], dv2 * hn[3]);
}

__global__ void k_fin42(const float* __restrict__ agg, float* __restrict__ h3,
                        float* __restrict__ agg3, const float* __restrict__ dinv,
                        const float* __restrict__ W, const float* __restrict__ b, int n) {
    int i = blockIdx.x * blockDim.x + threadIdx.x;
    if (i >= n) return;
    float4 a = ((const float4*)agg)[i];
    float t0 = tanhf(a.x + b[0]);
    float t1 = tanhf(a.y + b[1]);
    float t2 = tanhf(a.z + b[2]);
    float t3 = tanhf(a.w + b[3]);
    float h0 = t0 * W[0] + t1 * W[2] + t2 * W[4] + t3 * W[6];
    float h1 = t0 * W[1] + t1 * W[3] + t2 * W[5] + t3 * W[7];
    float dv = dinv[i], dv2 = dv * dv;
    ((float2*)h3)[i] = make_float2(h0, h1);
    ((float2*)agg3)[i] = make_float2(dv2 * h0, dv2 * h1);
}

__global__ void k_final_old(const float* __restrict__ agg3,
                            const float* __restrict__ Wc, const float* __restrict__ b3,
                            const float* __restrict__ bc,
                            float* __restrict__ out, float* __restrict__ hout, int n) {
    int i = blockIdx.x * blockDim.x + threadIdx.x;
    if (i >= n) return;
    float2 a = ((const float2*)agg3)[i];
    float t0 = tanhf(a.x + b3[0]);
    float t1 = tanhf(a.y + b3[1]);
    ((float2*)hout)[i] = make_float2(t0, t1);
    float4* o = (float4*)(out + (size_t)i * 16);
#pragma unroll
    for (int q = 0; q < 4; q++) {
        float4 v;
        v.x = t0 * Wc[4 * q + 0] + t1 * Wc[16 + 4 * q + 0] + bc[4 * q + 0];
        v.y = t0 * Wc[4 * q + 1] + t1 * Wc[16 + 4 * q + 1] + bc[4 * q + 1];
        v.z = t0 * Wc[4 * q + 2] + t1 * Wc[16 + 4 * q + 2] + bc[4 * q + 2];
        v.w = t0 * Wc[4 * q + 3] + t1 * Wc[16 + 4 * q + 3] + bc[4 * q + 3];
        o[q] = v;
    }
}

// ---------------- launcher ----------------

extern "C" void kernel_launch(void* const* d_in, const int* in_sizes, int n_in,
                              void* d_out, int out_size, void* d_ws, size_t ws_size,
                              hipStream_t stream) {
    const float* x   = (const float*)d_in[0];
    const float* W1  = (const float*)d_in[1];
    const float* b1  = (const float*)d_in[2];
    const float* W2  = (const float*)d_in[3];
    const float* b2  = (const float*)d_in[4];
    const float* W3  = (const float*)d_in[5];
    const float* b3  = (const float*)d_in[6];
    const float* Wc  = (const float*)d_in[7];
    const float* bc  = (const float*)d_in[8];
    const int* eidx  = (const int*)d_in[9];

    const int n = in_sizes[0] / 128;   // 200000
    const int e = in_sizes[9] / 2;     // 6400000
    const int* src = eidx;
    const int* dst = eidx + e;

    float* out_c = (float*)d_out;                   // [n,16]
    float* out_h = (float*)d_out + 16 * (size_t)n;  // [n,2]

    const int B = 256;
    const int gn = (n + B - 1) / B;
    const int ge = (e + B - 1) / B;
    const int nbE = (e + EPB - 1) / EPB;            // build blocks (391)
    const int nbL = (n + LINR - 1) / LINR;          // lin-role blocks

    size_t nP = ((size_t)(n + 4) + 3) & ~(size_t)3; // +1 zeroed sentinel row

    // fast-path workspace layout (csrp has 4096-int slack for tail overreads)
    int* csrp    = (int*)d_ws;                         // NR*CAP + 4096
    int* cursor  = csrp + (size_t)NR * CAP + 4096;     // NR*16
    int* split   = cursor + NR * 16;                   // NR*4
    float* dinv  = (float*)(split + NR * 4);
    float* h1    = dinv + nP;                 // 4nP
    float* g1    = h1 + 4 * nP;               // 4nP
    float* g2    = g1 + 4 * nP;               // 4nP
    float* g3    = g2 + 4 * nP;               // 2nP
    size_t need  = (size_t)((char*)(g3 + 2 * nP) - (char*)d_ws);

    bool fast = (ws_size >= need) && (n <= NR * RNG) && (n < (1 << 18));

    if (fast) {
        k_initcur<<<(NR + 255) / 256, 256, 0, stream>>>(cursor, g1, g2, g3, n);
        k_build_lin<<<nbE + nbL, HB, 0, stream>>>(src, dst, cursor, csrp,
                                                  x, W1, (float4*)h1, e, n, nbE);
        k_sortbin<<<NR, 1024, 0, stream>>>(csrp, cursor, split, dinv,
                                           (const float4*)h1, (float4*)g1, n);

        k_bagg44s<<<NR * 4, 256, 0, stream>>>(csrp, split, dinv, (const float4*)g1,
                                              (float4*)g2, W2, b1, n);
        k_bagg42s<<<NR * 4, 256, 0, stream>>>(csrp, split, dinv, (const float4*)g2,
                                              (float2*)g3, W3, b2, n);
        k_bagg2outs<<<NR * 4, 256, 0, stream>>>(csrp, split, dinv, (const float2*)g3,
                                                b3, Wc, bc, out_c, (float2*)out_h, n);
    } else {
        // fallback: push-atomic path (~11MB ws)
        int* fcnt   = (int*)d_ws;
        float* fdnv = (float*)d_ws + nP;
        float* h    = fdnv + nP;
        float* agg  = h + 4 * nP;
        float* h3   = agg + 4 * nP;
        float* agg3 = h3 + 2 * nP;

        hipMemsetAsync(fcnt, 0, (size_t)n * sizeof(int), stream);
        k_count<<<ge, B, 0, stream>>>(dst, fcnt, e);
        k_dinv_i<<<gn, B, 0, stream>>>(fcnt, fdnv, n);
        f_linear1<<<(n + 3) / 4, B, 0, stream>>>(x, W1, fdnv, h, agg, n);
        k_edge4<<<ge, B, 0, stream>>>(src, dst, fdnv, h, agg, e);
        k_fin44<<<gn, B, 0, stream>>>(h, agg, fdnv, W2, b1, n);
        k_edge4<<<ge, B, 0, stream>>>(src, dst, fdnv, h, agg, e);
        k_fin42<<<gn, B, 0, stream>>>(agg, h3, agg3, fdnv, W3, b2, n);
        k_edge2<<<ge, B, 0, stream>>>(src, dst, fdnv, h3, agg3, e);
        k_final_old<<<gn, B, 0, stream>>>(agg3, Wc, b3, bc, out_c, (float*)out_h, n);
    }
}